// Round 2
// baseline (2076.345 us; speedup 1.0000x reference)
//
#include <hip/hip_runtime.h>

#define BDIM 4
#define LDIM 4096
#define DDIM 1024
#define KTAPS 128

typedef __attribute__((ext_vector_type(8))) short bf16x8;
typedef __attribute__((ext_vector_type(4))) float f32x4;

// ---------------------------------------------------------------------------
// bf16 split helpers (hi = RNE(f), lo = RNE(f - hi))
// ---------------------------------------------------------------------------
__device__ __forceinline__ ushort bf16_rne(float f) {
    unsigned u = __float_as_uint(f);
    u += 0x7FFFu + ((u >> 16) & 1u);
    return (ushort)(u >> 16);
}
__device__ __forceinline__ float bf16_to_f(ushort h) {
    return __uint_as_float(((unsigned)h) << 16);
}

__device__ __forceinline__ void load_lds16(const ushort* g, ushort* l) {
    __builtin_amdgcn_global_load_lds(
        (const __attribute__((address_space(1))) void*)g,
        (__attribute__((address_space(3))) void*)l, 16, 0, 0);
}

// granule swizzle for LDS row r (4 granules of 16B per 64B row)
#define NSWZ(r) ((((r) & 3) ^ (((r) >> 2) & 3)))

// ---------------------------------------------------------------------------
// split_cat: fp32 [rows,1024] -> bf16 [rows,3072]
// mode 0 (A-pattern): [hi | hi | lo]      mode 1 (B-pattern): [hi | lo | hi]
// ---------------------------------------------------------------------------
__global__ __launch_bounds__(256) void split_cat(const float* __restrict__ in,
                                                 ushort* __restrict__ out,
                                                 int n4, int mode) {
    const int cols4 = DDIM / 4;
    for (int i = blockIdx.x * 256 + threadIdx.x; i < n4; i += gridDim.x * 256) {
        const int row = i / cols4;
        const int c4 = i - row * cols4;
        const float4 v = *(const float4*)&in[(size_t)row * DDIM + c4 * 4];
        ushort4 hi, lo;
        hi.x = bf16_rne(v.x); lo.x = bf16_rne(v.x - bf16_to_f(hi.x));
        hi.y = bf16_rne(v.y); lo.y = bf16_rne(v.y - bf16_to_f(hi.y));
        hi.z = bf16_rne(v.z); lo.z = bf16_rne(v.z - bf16_to_f(hi.z));
        hi.w = bf16_rne(v.w); lo.w = bf16_rne(v.w - bf16_to_f(hi.w));
        const size_t o = (size_t)row * (3 * DDIM) + c4 * 4;
        *(ushort4*)&out[o] = hi;
        if (mode == 0) {
            *(ushort4*)&out[o + DDIM] = hi;
            *(ushort4*)&out[o + 2 * DDIM] = lo;
        } else {
            *(ushort4*)&out[o + DDIM] = lo;
            *(ushort4*)&out[o + 2 * DDIM] = hi;
        }
    }
}

// ---------------------------------------------------------------------------
// bf16 NT GEMM, m97 structure: 128x128 tile, BK=32, 4 waves, 16x16x32 MFMA.
// A [M,Kc] bf16 row-major, B [N,Kc] bf16 row-major, C [M,ldc] fp32.
// LDS staged via global_load_lds w/ pre-swizzled source granules.
// ---------------------------------------------------------------------------
__global__ __launch_bounds__(256) void gemm_bf16(const ushort* __restrict__ A,
                                                 const ushort* __restrict__ B,
                                                 float* __restrict__ C, int ldc, int Kc) {
    __shared__ ushort As[128 * 32];
    __shared__ ushort Bs[128 * 32];

    const int tid = threadIdx.x;
    const int m0 = blockIdx.y * 128;
    const int n0 = blockIdx.x * 128;

    // staging assignment: linear granule t -> (row t>>2, granule t&3); rows 64..127 via t+256
    const int ra = tid >> 2;
    const int ga = tid & 3;
    const int gs = (ga ^ NSWZ(ra)) * 8;  // pre-swizzled source granule (rows r and r+64 share low 4 bits)

    const ushort* srcA0 = A + (size_t)(m0 + ra) * Kc + gs;
    const ushort* srcA1 = A + (size_t)(m0 + 64 + ra) * Kc + gs;
    const ushort* srcB0 = B + (size_t)(n0 + ra) * Kc + gs;
    const ushort* srcB1 = B + (size_t)(n0 + 64 + ra) * Kc + gs;
    ushort* dstA0 = &As[tid * 8];
    ushort* dstA1 = &As[(tid + 256) * 8];
    ushort* dstB0 = &Bs[tid * 8];
    ushort* dstB1 = &Bs[(tid + 256) * 8];

    const int lane = tid & 63;
    const int w = tid >> 6;
    const int wr = w >> 1, wc = w & 1;      // wave 64x64 sub-tile
    const int r16 = lane & 15;
    const int kg = lane >> 4;
    const int kidx = (kg ^ NSWZ(r16)) * 8;  // swizzled ds_read granule
    const int arow = wr * 64 + r16;
    const int brow = wc * 64 + r16;

    f32x4 acc[4][4] = {};

    for (int kc = 0; kc < Kc; kc += 32) {
        __syncthreads();  // previous iteration's LDS reads complete
        load_lds16(srcA0, dstA0);
        load_lds16(srcA1, dstA1);
        load_lds16(srcB0, dstB0);
        load_lds16(srcB1, dstB1);
        srcA0 += 32; srcA1 += 32; srcB0 += 32; srcB1 += 32;
        __syncthreads();  // vmcnt drained before barrier -> tiles visible

        bf16x8 a[4], b[4];
#pragma unroll
        for (int i = 0; i < 4; ++i) a[i] = *(const bf16x8*)&As[(arow + i * 16) * 32 + kidx];
#pragma unroll
        for (int i = 0; i < 4; ++i) b[i] = *(const bf16x8*)&Bs[(brow + i * 16) * 32 + kidx];
#pragma unroll
        for (int i = 0; i < 4; ++i)
#pragma unroll
            for (int j = 0; j < 4; ++j)
                acc[i][j] = __builtin_amdgcn_mfma_f32_16x16x32_bf16(a[i], b[j], acc[i][j], 0, 0, 0);
    }

#pragma unroll
    for (int i = 0; i < 4; ++i) {
        const int row = m0 + wr * 64 + i * 16 + kg * 4;
#pragma unroll
        for (int j = 0; j < 4; ++j) {
            const int col = n0 + wc * 64 + j * 16 + r16;
#pragma unroll
            for (int q = 0; q < 4; ++q)
                C[(size_t)(row + q) * ldc + col] = acc[i][j][q];
        }
    }
}

// ---------------------------------------------------------------------------
// conv + gate, split-write into GEMM2's A-cat buffer [hi|hi|lo].
// decay geometric => IIR: res[l] = r*res[l-1] + src[l] - decay128*src[l-128]
// ---------------------------------------------------------------------------
#define LCHUNK 128
__device__ __forceinline__ void store_g(ushort* p, float g) {
    const ushort hi = bf16_rne(g);
    const ushort lo = bf16_rne(g - bf16_to_f(hi));
    p[0] = hi;
    p[DDIM] = hi;
    p[2 * DDIM] = lo;
}

__global__ __launch_bounds__(256) void conv_gate_split(const float* __restrict__ qkv,
                                                       const float* __restrict__ decay,
                                                       ushort* __restrict__ gcat) {
    __shared__ float sdec[KTAPS];
    if (threadIdx.x < KTAPS) sdec[threadIdx.x] = decay[threadIdx.x];
    __syncthreads();

    const int d = blockIdx.y * 256 + threadIdx.x;
    const int b = blockIdx.z;
    const int l0 = blockIdx.x * LCHUNK;

    const float r = sdec[1];
    const float dlast = r * sdec[KTAPS - 1];
    const size_t rs = 3 * DDIM;

    const float* base = qkv + (size_t)b * LDIM * rs;
    const float* qc = base + d;
    const float* kc = base + DDIM + d;
    const float* vc = base + 2 * DDIM + d;
    ushort* g0 = gcat + (size_t)b * LDIM * rs + d;

    float res = 0.f;
    int lstart;
    if (l0 == 0) {
        lstart = 0;
    } else {
#pragma unroll 4
        for (int t = 0; t < KTAPS; ++t) {
            const size_t off = (size_t)(l0 - t) * rs;
            res += sdec[t] * kc[off] * vc[off];
        }
        store_g(g0 + (size_t)l0 * rs, qc[(size_t)l0 * rs] * res);
        lstart = l0 + 1;
    }

    for (int l = lstart; l < l0 + LCHUNK; ++l) {
        const size_t off = (size_t)l * rs;
        const float s = kc[off] * vc[off];
        if (l == 0) {
            res = sdec[0] * s;
        } else {
            float sub = 0.f;
            if (l >= KTAPS) {
                const size_t o2 = (size_t)(l - KTAPS) * rs;
                sub = dlast * kc[o2] * vc[o2];
            }
            res = r * res + s - sub;
        }
        store_g(g0 + off, qc[off] * res);
    }
}

// ---------------------------------------------------------------------------
// Fallback fp32 path (round-1, proven) if ws_size < 306MB
// ---------------------------------------------------------------------------
template <int BM, int BN, int BK>
__global__ __launch_bounds__(256) void gemm_nt(const float* __restrict__ A, int lda,
                                               const float* __restrict__ B, int ldb,
                                               float* __restrict__ C, int ldc, int K) {
    __shared__ float Asf[BK][BM + 4];
    __shared__ float Bsf[BK][BN + 4];
    const int tid = threadIdx.x;
    const int m0 = blockIdx.y * BM;
    const int n0 = blockIdx.x * BN;
    const int srow = tid >> 2;
    const int skq = (tid & 3) << 2;
    const int tx = tid & 15;
    const int ty = tid >> 4;
    float acc[8][8];
#pragma unroll
    for (int i = 0; i < 8; ++i)
#pragma unroll
        for (int j = 0; j < 8; ++j) acc[i][j] = 0.f;
    for (int k0 = 0; k0 < K; k0 += BK) {
        const float4 a0 = *(const float4*)&A[(size_t)(m0 + srow) * lda + k0 + skq];
        const float4 a1 = *(const float4*)&A[(size_t)(m0 + srow + 64) * lda + k0 + skq];
        const float4 b0 = *(const float4*)&B[(size_t)(n0 + srow) * ldb + k0 + skq];
        const float4 b1 = *(const float4*)&B[(size_t)(n0 + srow + 64) * ldb + k0 + skq];
        __syncthreads();
        Asf[skq + 0][srow] = a0.x; Asf[skq + 1][srow] = a0.y;
        Asf[skq + 2][srow] = a0.z; Asf[skq + 3][srow] = a0.w;
        Asf[skq + 0][srow + 64] = a1.x; Asf[skq + 1][srow + 64] = a1.y;
        Asf[skq + 2][srow + 64] = a1.z; Asf[skq + 3][srow + 64] = a1.w;
        Bsf[skq + 0][srow] = b0.x; Bsf[skq + 1][srow] = b0.y;
        Bsf[skq + 2][srow] = b0.z; Bsf[skq + 3][srow] = b0.w;
        Bsf[skq + 0][srow + 64] = b1.x; Bsf[skq + 1][srow + 64] = b1.y;
        Bsf[skq + 2][srow + 64] = b1.z; Bsf[skq + 3][srow + 64] = b1.w;
        __syncthreads();
#pragma unroll
        for (int kk = 0; kk < BK; ++kk) {
            float av[8], bv[8];
            *(float4*)&av[0] = *(const float4*)&Asf[kk][ty * 4];
            *(float4*)&av[4] = *(const float4*)&Asf[kk][64 + ty * 4];
            *(float4*)&bv[0] = *(const float4*)&Bsf[kk][tx * 4];
            *(float4*)&bv[4] = *(const float4*)&Bsf[kk][64 + tx * 4];
#pragma unroll
            for (int i = 0; i < 8; ++i)
#pragma unroll
                for (int j = 0; j < 8; ++j) acc[i][j] += av[i] * bv[j];
        }
    }
#pragma unroll
    for (int i = 0; i < 8; ++i) {
        const int row = m0 + ((i < 4) ? (ty * 4 + i) : (64 + ty * 4 + (i - 4)));
        float4 c0 = make_float4(acc[i][0], acc[i][1], acc[i][2], acc[i][3]);
        float4 c1 = make_float4(acc[i][4], acc[i][5], acc[i][6], acc[i][7]);
        *(float4*)&C[(size_t)row * ldc + n0 + tx * 4] = c0;
        *(float4*)&C[(size_t)row * ldc + n0 + 64 + tx * 4] = c1;
    }
}

__global__ __launch_bounds__(256) void conv_gate_inplace(float* __restrict__ qkv,
                                                         const float* __restrict__ decay) {
    __shared__ float sdec[KTAPS];
    if (threadIdx.x < KTAPS) sdec[threadIdx.x] = decay[threadIdx.x];
    __syncthreads();
    const int d = blockIdx.y * 256 + threadIdx.x;
    const int b = blockIdx.z;
    const int l0 = blockIdx.x * 512;
    const float r = sdec[1];
    const float dlast = r * sdec[KTAPS - 1];
    const size_t rs = 3 * DDIM;
    float* base = qkv + (size_t)b * LDIM * rs;
    float* qc = base + d;
    const float* kc = base + DDIM + d;
    const float* vc = base + 2 * DDIM + d;
    float res = 0.f;
    int lstart;
    if (l0 == 0) {
        lstart = 0;
    } else {
#pragma unroll 4
        for (int t = 0; t < KTAPS; ++t) {
            const size_t off = (size_t)(l0 - t) * rs;
            res += sdec[t] * kc[off] * vc[off];
        }
        qc[(size_t)l0 * rs] *= res;
        lstart = l0 + 1;
    }
    for (int l = lstart; l < l0 + 512; ++l) {
        const size_t off = (size_t)l * rs;
        const float s = kc[off] * vc[off];
        if (l == 0) {
            res = sdec[0] * s;
        } else {
            float sub = 0.f;
            if (l >= KTAPS) {
                const size_t o2 = (size_t)(l - KTAPS) * rs;
                sub = dlast * kc[o2] * vc[o2];
            }
            res = r * res + s - sub;
        }
        qc[off] *= res;
    }
}

// ---------------------------------------------------------------------------
extern "C" void kernel_launch(void* const* d_in, const int* in_sizes, int n_in,
                              void* d_out, int out_size, void* d_ws, size_t ws_size,
                              hipStream_t stream) {
    const float* x = (const float*)d_in[0];
    const float* Wqkv = (const float*)d_in[1];
    const float* Wout = (const float*)d_in[2];
    const float* decay = (const float*)d_in[3];
    float* out = (float*)d_out;

    const int M = BDIM * LDIM;  // 16384
    const size_t catA_b = (size_t)M * 3072 * 2;       // 96 MB (xcat, then gcat)
    const size_t catB_b = (size_t)3072 * 3072 * 2;    // 18 MB
    const size_t qkv_b = (size_t)M * 3072 * 4;        // 192 MB
    const size_t need = catA_b + catB_b + qkv_b;

    if (ws_size >= need) {
        ushort* cat = (ushort*)d_ws;
        ushort* wcat = (ushort*)((char*)d_ws + catA_b);
        float* qkv = (float*)((char*)d_ws + catA_b + catB_b);

        // prep: split x and Wqkv into cat-K bf16 layout
        split_cat<<<2048, 256, 0, stream>>>(x, cat, M * DDIM / 4, 0);
        split_cat<<<1024, 256, 0, stream>>>(Wqkv, wcat, 3 * DDIM * DDIM / 4, 1);

        // GEMM1: qkv = x @ Wqkv^T  (split-K' = 3072)
        dim3 g1(3 * DDIM / 128, M / 128);
        gemm_bf16<<<g1, 256, 0, stream>>>(cat, wcat, qkv, 3 * DDIM, 3072);

        // conv + gate -> gcat (reuses xcat buffer)
        dim3 g2(LDIM / LCHUNK, DDIM / 256, BDIM);
        conv_gate_split<<<g2, 256, 0, stream>>>(qkv, decay, cat);

        // prep Wout (overwrites Wqkv cat, dead after GEMM1)
        split_cat<<<512, 256, 0, stream>>>(Wout, wcat, DDIM * DDIM / 4, 1);

        // GEMM2: out = gated @ Wout^T
        dim3 g3(DDIM / 128, M / 128);
        gemm_bf16<<<g3, 256, 0, stream>>>(cat, wcat, out, DDIM, 3072);
    } else {
        // fp32 fallback (round-1 path, needs 192MB)
        float* qkv = (float*)d_ws;
        dim3 g1(3 * DDIM / 128, M / 128);
        gemm_nt<128, 128, 16><<<g1, 256, 0, stream>>>(x, DDIM, Wqkv, DDIM, qkv, 3 * DDIM, DDIM);
        dim3 g2(LDIM / 512, DDIM / 256, BDIM);
        conv_gate_inplace<<<g2, 256, 0, stream>>>(qkv, decay);
        dim3 g3(DDIM / 128, M / 128);
        gemm_nt<128, 128, 16><<<g3, 256, 0, stream>>>(qkv, 3 * DDIM, Wout, DDIM, out, DDIM, DDIM);
    }
}

// Round 3
// 688.638 us; speedup vs baseline: 3.0151x; 3.0151x over previous
//
#include <hip/hip_runtime.h>

#define BDIM 4
#define LDIM 4096
#define DDIM 1024
#define KTAPS 128
#define KC 3072
#define LCHUNK 64

typedef __attribute__((ext_vector_type(8))) short bf16x8;
typedef __attribute__((ext_vector_type(4))) float f32x4;

// ---------------------------------------------------------------------------
// bf16 helpers
// ---------------------------------------------------------------------------
__device__ __forceinline__ ushort bf16_rne(float f) {
    unsigned u = __float_as_uint(f);
    u += 0x7FFFu + ((u >> 16) & 1u);
    return (ushort)(u >> 16);
}
__device__ __forceinline__ float bf16_to_f(ushort h) {
    return __uint_as_float(((unsigned)h) << 16);
}

__device__ __forceinline__ void load_lds16(const ushort* g, ushort* l) {
    __builtin_amdgcn_global_load_lds(
        (const __attribute__((address_space(1))) void*)g,
        (__attribute__((address_space(3))) void*)l, 16, 0, 0);
}

// granule swizzle for LDS row r (4 granules of 16B per 64B row); period-16 in r
#define NSWZ(r) ((((r) & 3) ^ (((r) >> 2) & 3)))

// ---------------------------------------------------------------------------
// split_cat: fp32 [rows,1024] -> bf16 [rows,3072]
// mode 0 (A-pattern): [hi | hi | lo]      mode 1 (B-pattern): [hi | lo | hi]
// Split GEMM: A=[ahi|ahi|alo] . B=[bhi|blo|bhi] over K'=3072 gives
// ahi.bhi + ahi.blo + alo.bhi  (drops only alo.blo ~ 4e-6 rel)
// ---------------------------------------------------------------------------
__global__ __launch_bounds__(256) void split_cat(const float* __restrict__ in,
                                                 ushort* __restrict__ out,
                                                 int n4, int mode) {
    const int cols4 = DDIM / 4;
    for (int i = blockIdx.x * 256 + threadIdx.x; i < n4; i += gridDim.x * 256) {
        const int row = i / cols4;
        const int c4 = i - row * cols4;
        const float4 v = *(const float4*)&in[(size_t)row * DDIM + c4 * 4];
        ushort4 hi, lo;
        hi.x = bf16_rne(v.x); lo.x = bf16_rne(v.x - bf16_to_f(hi.x));
        hi.y = bf16_rne(v.y); lo.y = bf16_rne(v.y - bf16_to_f(hi.y));
        hi.z = bf16_rne(v.z); lo.z = bf16_rne(v.z - bf16_to_f(hi.z));
        hi.w = bf16_rne(v.w); lo.w = bf16_rne(v.w - bf16_to_f(hi.w));
        const size_t o = (size_t)row * KC + c4 * 4;
        *(ushort4*)&out[o] = hi;
        if (mode == 0) {
            *(ushort4*)&out[o + DDIM] = hi;
            *(ushort4*)&out[o + 2 * DDIM] = lo;
        } else {
            *(ushort4*)&out[o + DDIM] = lo;
            *(ushort4*)&out[o + 2 * DDIM] = hi;
        }
    }
}

// ---------------------------------------------------------------------------
// bf16 NT GEMM (m97 structure): 128x128 tile, BK=32, 4 waves, 16x16x32 MFMA,
// global_load_lds w/ pre-swizzled source granules + swizzled ds_read.
// OBF=1 -> bf16 output, OBF=0 -> fp32 output. XCD-aware tile swizzle.
// ---------------------------------------------------------------------------
template <int OBF>
__global__ __launch_bounds__(256) void gemm_bf16(const ushort* __restrict__ A,
                                                 const ushort* __restrict__ B,
                                                 void* __restrict__ Cp, int ldc, int Kc) {
    __shared__ ushort As[128 * 32];
    __shared__ ushort Bs[128 * 32];

    const int tid = threadIdx.x;

    // bijective XCD swizzle (nwg % 8 == 0 for all our grids)
    const int gx = gridDim.x;
    const int nwg = gx * gridDim.y;
    const int orig = blockIdx.y * gx + blockIdx.x;
    const int q8 = nwg >> 3;
    const int tile = (orig & 7) * q8 + (orig >> 3);
    const int m0 = (tile / gx) * 128;
    const int n0 = (tile % gx) * 128;

    // staging: thread t -> LDS row t>>2 (and +64), granule t&3; inverse-swizzled source
    const int ra = tid >> 2;
    const int ga = tid & 3;
    const int gs = (ga ^ NSWZ(ra)) * 8;

    const ushort* srcA0 = A + (size_t)(m0 + ra) * Kc + gs;
    const ushort* srcA1 = A + (size_t)(m0 + 64 + ra) * Kc + gs;
    const ushort* srcB0 = B + (size_t)(n0 + ra) * Kc + gs;
    const ushort* srcB1 = B + (size_t)(n0 + 64 + ra) * Kc + gs;
    ushort* dstA0 = &As[tid * 8];
    ushort* dstA1 = &As[(tid + 256) * 8];
    ushort* dstB0 = &Bs[tid * 8];
    ushort* dstB1 = &Bs[(tid + 256) * 8];

    const int lane = tid & 63;
    const int w = tid >> 6;
    const int wr = w >> 1, wc = w & 1;  // wave 64x64 sub-tile
    const int r16 = lane & 15;
    const int kg = lane >> 4;
    const int kidx = (kg ^ NSWZ(r16)) * 8;  // swizzled ds_read granule
    const int arow = wr * 64 + r16;
    const int brow = wc * 64 + r16;

    f32x4 acc[4][4] = {};

    for (int kc = 0; kc < Kc; kc += 32) {
        __syncthreads();  // prior iteration's ds_reads are done (lgkm waits precede mfma)
        load_lds16(srcA0, dstA0);
        load_lds16(srcA1, dstA1);
        load_lds16(srcB0, dstB0);
        load_lds16(srcB1, dstB1);
        srcA0 += 32; srcA1 += 32; srcB0 += 32; srcB1 += 32;
        __syncthreads();  // vmcnt(0) drained before barrier -> tiles visible

        bf16x8 a[4], b[4];
#pragma unroll
        for (int i = 0; i < 4; ++i) a[i] = *(const bf16x8*)&As[(arow + i * 16) * 32 + kidx];
#pragma unroll
        for (int i = 0; i < 4; ++i) b[i] = *(const bf16x8*)&Bs[(brow + i * 16) * 32 + kidx];
#pragma unroll
        for (int i = 0; i < 4; ++i)
#pragma unroll
            for (int j = 0; j < 4; ++j)
                acc[i][j] = __builtin_amdgcn_mfma_f32_16x16x32_bf16(a[i], b[j], acc[i][j], 0, 0, 0);
    }

    // C/D layout (m89-verified): col = lane&15, row = (lane>>4)*4 + q
#pragma unroll
    for (int i = 0; i < 4; ++i) {
        const int row = m0 + wr * 64 + i * 16 + kg * 4;
#pragma unroll
        for (int j = 0; j < 4; ++j) {
            const int col = n0 + wc * 64 + j * 16 + r16;
#pragma unroll
            for (int q = 0; q < 4; ++q) {
                if (OBF) {
                    ((ushort*)Cp)[(size_t)(row + q) * ldc + col] = bf16_rne(acc[i][j][q]);
                } else {
                    ((float*)Cp)[(size_t)(row + q) * ldc + col] = acc[i][j][q];
                }
            }
        }
    }
}

// ---------------------------------------------------------------------------
// conv + gate on bf16 qkv; writes split [hi|hi|lo] into GEMM2's A-cat buffer.
// decay geometric => exact IIR for the 128-tap FIR:
//   res[l] = r*res[l-1] + src[l] - decay128*src[l-128],  src = k*v
// Chunks of LCHUNK=64 per block; each seeds with a direct tap sum.
// ---------------------------------------------------------------------------
__global__ __launch_bounds__(256) void conv_gate_bf16(const ushort* __restrict__ qkvh,
                                                      const float* __restrict__ decay,
                                                      ushort* __restrict__ gcat) {
    __shared__ float sdec[KTAPS];
    if (threadIdx.x < KTAPS) sdec[threadIdx.x] = decay[threadIdx.x];
    __syncthreads();

    const int d = blockIdx.y * 256 + threadIdx.x;
    const int b = blockIdx.z;
    const int l0 = blockIdx.x * LCHUNK;

    const float r = sdec[1];
    const float dlast = r * sdec[KTAPS - 1];  // decay[128]
    const size_t rs = KC;

    const ushort* base = qkvh + (size_t)b * LDIM * rs;
    const ushort* qc = base + d;
    const ushort* kc = base + DDIM + d;
    const ushort* vc = base + 2 * DDIM + d;
    ushort* g0 = gcat + (size_t)b * LDIM * rs + d;

    float res = 0.f;
    int lstart;
    if (l0 == 0) {
        lstart = 0;
    } else {
        const int tmax = (l0 < KTAPS - 1) ? l0 : (KTAPS - 1);
#pragma unroll 4
        for (int t = 0; t <= tmax; ++t) {
            const size_t off = (size_t)(l0 - t) * rs;
            res += sdec[t] * bf16_to_f(kc[off]) * bf16_to_f(vc[off]);
        }
        const float g = bf16_to_f(qc[(size_t)l0 * rs]) * res;
        const ushort hi = bf16_rne(g);
        const ushort lo = bf16_rne(g - bf16_to_f(hi));
        ushort* p = g0 + (size_t)l0 * rs;
        p[0] = hi; p[DDIM] = hi; p[2 * DDIM] = lo;
        lstart = l0 + 1;
    }

    for (int l = lstart; l < l0 + LCHUNK; ++l) {
        const size_t off = (size_t)l * rs;
        const float s = bf16_to_f(kc[off]) * bf16_to_f(vc[off]);
        if (l == 0) {
            res = sdec[0] * s;
        } else {
            float sub = 0.f;
            if (l >= KTAPS) {
                const size_t o2 = (size_t)(l - KTAPS) * rs;
                sub = dlast * bf16_to_f(kc[o2]) * bf16_to_f(vc[o2]);
            }
            res = r * res + s - sub;
        }
        const float g = bf16_to_f(qc[off]) * res;
        const ushort hi = bf16_rne(g);
        const ushort lo = bf16_rne(g - bf16_to_f(hi));
        ushort* p = g0 + off;
        p[0] = hi; p[DDIM] = hi; p[2 * DDIM] = lo;
    }
}

// ---------------------------------------------------------------------------
// Memory plan (ws proven >= 192MB in round 1; need EXACTLY 192MB):
//   ws[  0.. 96MB) qkvh bf16 [M,3072]   (GEMM1 out; dead after conv ->
//                                        first 6MB reused for Wout-cat)
//   ws[ 96..192MB) gcat bf16 [M,3072]   (conv out = GEMM2 A)
//   d_out[ 0..24MB) xcat_b bf16 [4096,3072]  per-batch GEMM1 A staging
//   d_out[24..42MB) Wqkv-cat bf16 [3072,3072]
//   GEMM2 reads only ws, writes all 64MB of d_out (xcat/wcat dead).
// ---------------------------------------------------------------------------
extern "C" void kernel_launch(void* const* d_in, const int* in_sizes, int n_in,
                              void* d_out, int out_size, void* d_ws, size_t ws_size,
                              hipStream_t stream) {
    const float* x = (const float*)d_in[0];
    const float* Wqkv = (const float*)d_in[1];
    const float* Wout = (const float*)d_in[2];
    const float* decay = (const float*)d_in[3];

    const int M = BDIM * LDIM;  // 16384

    ushort* qkvh = (ushort*)d_ws;                                  // 96 MB
    ushort* gcat = (ushort*)((char*)d_ws + (size_t)96 * 1024 * 1024);  // 96 MB
    ushort* woutcat = (ushort*)d_ws;                               // 6 MB, after conv
    ushort* xcat_b = (ushort*)d_out;                               // 24 MB
    ushort* wqkvcat = (ushort*)((char*)d_out + (size_t)24 * 1024 * 1024);  // 18 MB

    // Wqkv -> [hi|lo|hi] cat
    split_cat<<<1024, 256, 0, stream>>>(Wqkv, wqkvcat, KC * DDIM / 4, 1);

    // per-batch: x_b -> [hi|hi|lo] cat; GEMM1 -> qkvh[b] (bf16 out)
    for (int b = 0; b < BDIM; ++b) {
        split_cat<<<2048, 256, 0, stream>>>(x + (size_t)b * LDIM * DDIM, xcat_b,
                                            LDIM * DDIM / 4, 0);
        dim3 g1(KC / 128, LDIM / 128);  // 24 x 32 = 768 wgs (%8==0)
        gemm_bf16<1><<<g1, 256, 0, stream>>>(xcat_b, wqkvcat,
                                             qkvh + (size_t)b * LDIM * KC, KC, KC);
    }

    // conv + gate -> gcat (one launch, 64x4x4 = 1024 blocks)
    dim3 g2(LDIM / LCHUNK, DDIM / 256, BDIM);
    conv_gate_bf16<<<g2, 256, 0, stream>>>(qkvh, decay, gcat);

    // Wout -> [hi|lo|hi] cat (into dead qkvh region)
    split_cat<<<512, 256, 0, stream>>>(Wout, woutcat, DDIM * DDIM / 4, 1);

    // GEMM2: out = gcat @ woutcat^T (fp32 out)
    dim3 g3(DDIM / 128, M / 128);  // 8 x 128 = 1024 wgs (%8==0)
    gemm_bf16<0><<<g3, 256, 0, stream>>>(gcat, woutcat, d_out, DDIM, KC);
}

// Round 4
// 302.135 us; speedup vs baseline: 6.8722x; 2.2792x over previous
//
#include <hip/hip_runtime.h>

#define BDIM 4
#define LDIM 4096
#define DDIM 1024
#define KTAPS 128
#define LCHUNK 64

typedef __attribute__((ext_vector_type(8))) _Float16 f16x8;
typedef __attribute__((ext_vector_type(4))) float f32x4;

// ---------------------------------------------------------------------------
// fp16 helpers
// ---------------------------------------------------------------------------
__device__ __forceinline__ float f16_to_f(ushort h) {
    return (float)__builtin_bit_cast(_Float16, h);
}
__device__ __forceinline__ ushort f_to_f16(float f) {
    return __builtin_bit_cast(ushort, (_Float16)f);  // v_cvt_f16_f32, RNE
}

__device__ __forceinline__ void load_lds16(const ushort* g, ushort* l) {
    __builtin_amdgcn_global_load_lds(
        (const __attribute__((address_space(1))) void*)g,
        (__attribute__((address_space(3))) void*)l, 16, 0, 0);
}

// granule swizzle for LDS row r (4 granules of 16B per 64B row); period-16 in r
#define NSWZ(r) ((((r) & 3) ^ (((r) >> 2) & 3)))

// ---------------------------------------------------------------------------
// fp32 -> fp16 convert (vectorized, grid-stride)
// ---------------------------------------------------------------------------
__global__ __launch_bounds__(256) void to_f16(const float* __restrict__ in,
                                              ushort* __restrict__ out, int n4) {
    for (int i = blockIdx.x * 256 + threadIdx.x; i < n4; i += gridDim.x * 256) {
        const float4 v = *(const float4*)&in[(size_t)i * 4];
        ushort4 h;
        h.x = f_to_f16(v.x);
        h.y = f_to_f16(v.y);
        h.z = f_to_f16(v.z);
        h.w = f_to_f16(v.w);
        *(ushort4*)&out[(size_t)i * 4] = h;
    }
}

// ---------------------------------------------------------------------------
// fp16 NT GEMM (m97 structure): 128x128 tile, BK=32, 4 waves, 16x16x32 MFMA,
// global_load_lds w/ pre-swizzled source granules + swizzled ds_read.
// OBF=1 -> fp16 output, OBF=0 -> fp32 output. XCD-aware tile swizzle.
// A [M,Kc] f16 row-major, B [N,Kc] f16 row-major.
// ---------------------------------------------------------------------------
template <int OBF>
__global__ __launch_bounds__(256) void gemm_f16(const ushort* __restrict__ A,
                                                const ushort* __restrict__ B,
                                                void* __restrict__ Cp, int ldc, int Kc) {
    __shared__ ushort As[128 * 32];
    __shared__ ushort Bs[128 * 32];

    const int tid = threadIdx.x;

    // bijective XCD swizzle (nwg % 8 == 0 for all our grids)
    const int gx = gridDim.x;
    const int nwg = gx * gridDim.y;
    const int orig = blockIdx.y * gx + blockIdx.x;
    const int q8 = nwg >> 3;
    const int tile = (orig & 7) * q8 + (orig >> 3);
    const int m0 = (tile / gx) * 128;
    const int n0 = (tile % gx) * 128;

    // staging: thread t -> LDS rows t>>2 and t>>2 + 64, granule t&3; inverse-swizzled src
    const int ra = tid >> 2;
    const int ga = tid & 3;
    const int gs = (ga ^ NSWZ(ra)) * 8;

    const ushort* srcA0 = A + (size_t)(m0 + ra) * Kc + gs;
    const ushort* srcA1 = A + (size_t)(m0 + 64 + ra) * Kc + gs;
    const ushort* srcB0 = B + (size_t)(n0 + ra) * Kc + gs;
    const ushort* srcB1 = B + (size_t)(n0 + 64 + ra) * Kc + gs;
    ushort* dstA0 = &As[tid * 8];
    ushort* dstA1 = &As[(tid + 256) * 8];
    ushort* dstB0 = &Bs[tid * 8];
    ushort* dstB1 = &Bs[(tid + 256) * 8];

    const int lane = tid & 63;
    const int w = tid >> 6;
    const int wr = w >> 1, wc = w & 1;  // wave 64x64 sub-tile
    const int r16 = lane & 15;
    const int kg = lane >> 4;
    const int kidx = (kg ^ NSWZ(r16)) * 8;  // swizzled ds_read granule
    const int arow = wr * 64 + r16;
    const int brow = wc * 64 + r16;

    f32x4 acc[4][4] = {};

    for (int kc = 0; kc < Kc; kc += 32) {
        __syncthreads();  // prior iteration's ds_reads complete
        load_lds16(srcA0, dstA0);
        load_lds16(srcA1, dstA1);
        load_lds16(srcB0, dstB0);
        load_lds16(srcB1, dstB1);
        srcA0 += 32; srcA1 += 32; srcB0 += 32; srcB1 += 32;
        __syncthreads();  // vmcnt(0) drained before barrier -> tiles visible

        f16x8 a[4], b[4];
#pragma unroll
        for (int i = 0; i < 4; ++i)
            a[i] = *(const f16x8*)&As[(arow + i * 16) * 32 + kidx];
#pragma unroll
        for (int i = 0; i < 4; ++i)
            b[i] = *(const f16x8*)&Bs[(brow + i * 16) * 32 + kidx];
#pragma unroll
        for (int i = 0; i < 4; ++i)
#pragma unroll
            for (int j = 0; j < 4; ++j)
                acc[i][j] = __builtin_amdgcn_mfma_f32_16x16x32_f16(a[i], b[j], acc[i][j], 0, 0, 0);
    }

    // C/D layout (m89-verified, dtype-independent): col = lane&15, row = (lane>>4)*4 + q
#pragma unroll
    for (int i = 0; i < 4; ++i) {
        const int row = m0 + wr * 64 + i * 16 + kg * 4;
#pragma unroll
        for (int j = 0; j < 4; ++j) {
            const int col = n0 + wc * 64 + j * 16 + r16;
#pragma unroll
            for (int q = 0; q < 4; ++q) {
                if (OBF) {
                    ((ushort*)Cp)[(size_t)(row + q) * ldc + col] = f_to_f16(acc[i][j][q]);
                } else {
                    ((float*)Cp)[(size_t)(row + q) * ldc + col] = acc[i][j][q];
                }
            }
        }
    }
}

// ---------------------------------------------------------------------------
// conv + gate on fp16 qkv [B,L,3072]; writes gated fp16 [B,L,1024].
// decay geometric => exact IIR for the 128-tap FIR:
//   res[l] = r*res[l-1] + src[l] - decay128*src[l-128],  src = k*v  (fp32 state)
// Chunks of LCHUNK=64 per block (1024 blocks); each seeds with a direct tap sum.
// ---------------------------------------------------------------------------
__global__ __launch_bounds__(256) void conv_gate_f16(const ushort* __restrict__ qkvh,
                                                     const float* __restrict__ decay,
                                                     ushort* __restrict__ gh) {
    __shared__ float sdec[KTAPS];
    if (threadIdx.x < KTAPS) sdec[threadIdx.x] = decay[threadIdx.x];
    __syncthreads();

    const int d = blockIdx.y * 256 + threadIdx.x;
    const int b = blockIdx.z;
    const int l0 = blockIdx.x * LCHUNK;

    const float r = sdec[1];
    const float dlast = r * sdec[KTAPS - 1];  // decay[128]
    const size_t rs = 3 * DDIM;

    const ushort* base = qkvh + (size_t)b * LDIM * rs;
    const ushort* qc = base + d;
    const ushort* kc = base + DDIM + d;
    const ushort* vc = base + 2 * DDIM + d;
    ushort* g0 = gh + (size_t)b * LDIM * DDIM + d;

    float res = 0.f;
    int lstart;
    if (l0 == 0) {
        lstart = 0;
    } else {
        const int tmax = (l0 < KTAPS - 1) ? l0 : (KTAPS - 1);
#pragma unroll 4
        for (int t = 0; t <= tmax; ++t) {
            const size_t off = (size_t)(l0 - t) * rs;
            res += sdec[t] * f16_to_f(kc[off]) * f16_to_f(vc[off]);
        }
        g0[(size_t)l0 * DDIM] = f_to_f16(f16_to_f(qc[(size_t)l0 * rs]) * res);
        lstart = l0 + 1;
    }

    for (int l = lstart; l < l0 + LCHUNK; ++l) {
        const size_t off = (size_t)l * rs;
        const float s = f16_to_f(kc[off]) * f16_to_f(vc[off]);
        if (l == 0) {
            res = sdec[0] * s;
        } else {
            float sub = 0.f;
            if (l >= KTAPS) {
                const size_t o2 = (size_t)(l - KTAPS) * rs;
                sub = dlast * f16_to_f(kc[o2]) * f16_to_f(vc[o2]);
            }
            res = r * res + s - sub;
        }
        g0[(size_t)l * DDIM] = f_to_f16(f16_to_f(qc[off]) * res);
    }
}

// ---------------------------------------------------------------------------
// Memory plan (ws proven >= 192MB; uses 168MB, d_out untouched until GEMM2):
//   ws[  0.. 96MB) qkvh  f16 [16384,3072]  GEMM1 out
//   ws[ 96..128MB) gh    f16 [16384,1024]  conv out = GEMM2 A
//   ws[128..160MB) xh    f16 [16384,1024]  GEMM1 A
//   ws[160..166MB) wqkvh f16 [3072,1024]   GEMM1 B
//   ws[166..168MB) wouth f16 [1024,1024]   GEMM2 B
// ---------------------------------------------------------------------------
extern "C" void kernel_launch(void* const* d_in, const int* in_sizes, int n_in,
                              void* d_out, int out_size, void* d_ws, size_t ws_size,
                              hipStream_t stream) {
    const float* x = (const float*)d_in[0];
    const float* Wqkv = (const float*)d_in[1];
    const float* Wout = (const float*)d_in[2];
    const float* decay = (const float*)d_in[3];

    const int M = BDIM * LDIM;  // 16384
    const size_t MB = 1024 * 1024;

    ushort* qkvh = (ushort*)d_ws;
    ushort* gh = (ushort*)((char*)d_ws + 96 * MB);
    ushort* xh = (ushort*)((char*)d_ws + 128 * MB);
    ushort* wqkvh = (ushort*)((char*)d_ws + 160 * MB);
    ushort* wouth = (ushort*)((char*)d_ws + 166 * MB);

    // converts
    to_f16<<<2048, 256, 0, stream>>>(x, xh, M * DDIM / 4);
    to_f16<<<1024, 256, 0, stream>>>(Wqkv, wqkvh, 3 * DDIM * DDIM / 4);
    to_f16<<<512, 256, 0, stream>>>(Wout, wouth, DDIM * DDIM / 4);

    // GEMM1: qkvh = xh @ wqkvh^T  [16384,1024]x[3072,1024]^T, fp16 out
    dim3 g1(3 * DDIM / 128, M / 128);  // 24 x 128 = 3072 wgs (%8==0)
    gemm_f16<1><<<g1, 256, 0, stream>>>(xh, wqkvh, qkvh, 3 * DDIM, DDIM);

    // conv + gate -> gh
    dim3 g2(LDIM / LCHUNK, DDIM / 256, BDIM);  // 64 x 4 x 4 = 1024 blocks
    conv_gate_f16<<<g2, 256, 0, stream>>>(qkvh, decay, gh);

    // GEMM2: out = gh @ wouth^T  [16384,1024]x[1024,1024]^T, fp32 out
    dim3 g3(DDIM / 128, M / 128);  // 8 x 128 = 1024 wgs (%8==0)
    gemm_f16<0><<<g3, 256, 0, stream>>>(gh, wouth, d_out, DDIM, DDIM);
}